// Round 5
// baseline (899.698 us; speedup 1.0000x reference)
//
#include <hip/hip_runtime.h>
#include <hip/hip_bf16.h>
#include <math.h>

#define N_NODES 100000
#define N_EDGES 1600000
#define D_IN 64
#define D_HID 64
#define D_OUT 40

// ---- zero a range of ints (no hipMemsetAsync — kernel-only zeroing) ----
__global__ __launch_bounds__(256) void k_zero(int* __restrict__ p, int n) {
    int i = blockIdx.x * 256 + threadIdx.x;
    if (i < n) p[i] = 0;
}

// ---- degree count (real edges only; self-loop added analytically) ----
__global__ __launch_bounds__(256) void k_deg(const int* __restrict__ col,
                                             int* __restrict__ deg) {
    int e = blockIdx.x * 256 + threadIdx.x;
    if (e < N_EDGES) atomicAdd(&deg[col[e]], 1);
}

// ---- dinv = rsqrt(deg + 1) ----
__global__ __launch_bounds__(256) void k_dinv(const int* __restrict__ deg,
                                              float* __restrict__ dinv) {
    int v = blockIdx.x * 256 + threadIdx.x;
    if (v < N_NODES) dinv[v] = rsqrtf((float)deg[v] + 1.0f);
}

// ---- layer1 GEMM: g1[v,j] = dinv[v] * sum_k x[v,k]*W1[k,j]  (64x64) ----
__global__ __launch_bounds__(256) void k_gemm1(const float* __restrict__ x,
                                               const float* __restrict__ W,
                                               const float* __restrict__ dinv,
                                               float* __restrict__ g) {
    __shared__ float Ws[64 * 64];
    __shared__ float xs[4][64];
    int tid = threadIdx.x;
    for (int i = tid; i < 64 * 64; i += 256) Ws[i] = W[i];
    int v0 = blockIdx.x * 4;
    for (int i = tid; i < 4 * 64; i += 256) xs[i >> 6][i & 63] = x[v0 * 64 + i];
    __syncthreads();
    int r = tid >> 6, j = tid & 63;
    float acc = 0.f;
#pragma unroll
    for (int k = 0; k < 64; k++) acc += xs[r][k] * Ws[k * 64 + j];
    int v = v0 + r;
    g[v * 64 + j] = acc * dinv[v];
}

// ---- edge scatter, 64 channels: wave per edge, lane = channel ----
__global__ __launch_bounds__(256) void k_scatter1(const int* __restrict__ ei,
                                                  const float* __restrict__ g,
                                                  float* __restrict__ agg) {
    int t = blockIdx.x * 256 + threadIdx.x;
    int e = t >> 6, j = t & 63;
    if (e < N_EDGES) {
        int r = ei[e];              // source (gather)
        int c = ei[N_EDGES + e];    // target (scatter)
        atomicAdd(&agg[c * 64 + j], g[r * 64 + j]);
    }
}

// ---- finalize1: h = relu(dinv*(agg+g) + b1), stored in-place into agg ----
__global__ __launch_bounds__(256) void k_fin1(const float* __restrict__ g,
                                              const float* __restrict__ dinv,
                                              const float* __restrict__ b1,
                                              float* __restrict__ agg) {
    int t = blockIdx.x * 256 + threadIdx.x;
    if (t < N_NODES * 64) {
        int v = t >> 6, j = t & 63;
        float h = dinv[v] * (agg[t] + g[t]) + b1[j];
        agg[t] = h > 0.f ? h : 0.f;
    }
}

// ---- layer2 GEMM: g2[v,j] = dinv[v] * sum_k h[v,k]*W2[k,j]  (64x40) ----
__global__ __launch_bounds__(256) void k_gemm2(const float* __restrict__ h,
                                               const float* __restrict__ W,
                                               const float* __restrict__ dinv,
                                               float* __restrict__ g2) {
    __shared__ float Ws[64 * 40];
    __shared__ float hs[4][64];
    int tid = threadIdx.x;
    for (int i = tid; i < 64 * 40; i += 256) Ws[i] = W[i];
    int v0 = blockIdx.x * 4;
    for (int i = tid; i < 4 * 64; i += 256) hs[i >> 6][i & 63] = h[v0 * 64 + i];
    __syncthreads();
    int r = tid >> 6, j = tid & 63;
    if (j < 40) {
        float acc = 0.f;
#pragma unroll
        for (int k = 0; k < 64; k++) acc += hs[r][k] * Ws[k * 40 + j];
        int v = v0 + r;
        g2[v * 40 + j] = acc * dinv[v];
    }
}

// ---- edge scatter, 40 channels: wave per edge, lanes 0..39 active ----
__global__ __launch_bounds__(256) void k_scatter2(const int* __restrict__ ei,
                                                  const float* __restrict__ g2,
                                                  float* __restrict__ agg2) {
    int t = blockIdx.x * 256 + threadIdx.x;
    int e = t >> 6, j = t & 63;
    if (e < N_EDGES && j < D_OUT) {
        int r = ei[e];
        int c = ei[N_EDGES + e];
        atomicAdd(&agg2[c * D_OUT + j], g2[r * D_OUT + j]);
    }
}

// ---- finalize2: logits = dinv*(agg2+g2)+b2 ; log_softmax ; FLOAT out ----
__global__ __launch_bounds__(256) void k_fin2(const float* __restrict__ g2,
                                              const float* __restrict__ agg2,
                                              const float* __restrict__ dinv,
                                              const float* __restrict__ b2v,
                                              float* __restrict__ out) {
    int tid = threadIdx.x;
    int v = blockIdx.x * 4 + (tid >> 6);
    int j = tid & 63;
    float logit = -INFINITY;
    if (j < D_OUT)
        logit = dinv[v] * (agg2[v * D_OUT + j] + g2[v * D_OUT + j]) + b2v[j];
    float m = logit;
#pragma unroll
    for (int o = 32; o > 0; o >>= 1) m = fmaxf(m, __shfl_xor(m, o, 64));
    float ex = (j < D_OUT) ? expf(logit - m) : 0.f;
    float s = ex;
#pragma unroll
    for (int o = 32; o > 0; o >>= 1) s += __shfl_xor(s, o, 64);
    if (j < D_OUT) out[v * D_OUT + j] = logit - m - logf(s);
}

extern "C" void kernel_launch(void* const* d_in, const int* in_sizes, int n_in,
                              void* d_out, int out_size, void* d_ws, size_t ws_size,
                              hipStream_t stream) {
    const float* x  = (const float*)d_in[0];
    const int*   ei = (const int*)d_in[1];
    const float* W1 = (const float*)d_in[2];
    const float* b1 = (const float*)d_in[3];
    const float* W2 = (const float*)d_in[4];
    const float* b2 = (const float*)d_in[5];
    float* out = (float*)d_out;   // reference output dtype is float32

    const int N = N_NODES;
    // Workspace: N*130 floats = 52 MB.
    int*   deg  = (int*)d_ws;                 // N ints
    float* agg  = (float*)d_ws + N;           // N*64: agg1 -> h (in-place) -> agg2
    float* g    = agg + (size_t)N * 64;       // N*64: g1, then g2 (packed N*40)
    float* dinv = g + (size_t)N * 64;         // N floats

    // zero deg + agg (contiguous N*65 ints)
    k_zero<<<(N * 65 + 255) / 256, 256, 0, stream>>>(deg, N * 65);

    k_deg<<<(N_EDGES + 255) / 256, 256, 0, stream>>>(ei + N_EDGES, deg);
    k_dinv<<<(N + 255) / 256, 256, 0, stream>>>(deg, dinv);
    k_gemm1<<<N / 4, 256, 0, stream>>>(x, W1, dinv, g);
    k_scatter1<<<N_EDGES / 4, 256, 0, stream>>>(ei, g, agg);
    k_fin1<<<(N * 64) / 256, 256, 0, stream>>>(g, dinv, b1, agg);
    k_gemm2<<<N / 4, 256, 0, stream>>>(agg, W2, dinv, g);
    // re-zero agg's first N*40 floats for agg2 (h fully consumed by gemm2)
    k_zero<<<(N * 40) / 256, 256, 0, stream>>>((int*)agg, N * 40);
    k_scatter2<<<N_EDGES / 4, 256, 0, stream>>>(ei, g, agg);
    k_fin2<<<N / 4, 256, 0, stream>>>(g, agg, dinv, b2, out);
}

// Round 6
// 576.261 us; speedup vs baseline: 1.5613x; 1.5613x over previous
//
#include <hip/hip_runtime.h>
#include <hip/hip_bf16.h>
#include <math.h>

#define N_NODES 100000
#define N_EDGES 1600000
#define D_IN 64
#define D_HID 64
#define D_OUT 40
#define NBLK ((N_NODES + 255) / 256)   // 391 scan blocks

// ---- zero ints (no hipMemsetAsync) ----
__global__ __launch_bounds__(256) void k_zero(int* __restrict__ p, int n) {
    int i = blockIdx.x * 256 + threadIdx.x;
    if (i < n) p[i] = 0;
}

// ---- in-degree histogram over real edges ----
__global__ __launch_bounds__(256) void k_deg(const int* __restrict__ col,
                                             int* __restrict__ deg) {
    int e = blockIdx.x * 256 + threadIdx.x;
    if (e < N_EDGES) atomicAdd(&deg[col[e]], 1);
}

// ---- dinv = rsqrt(deg + 1)  (self-loop in the +1) ----
__global__ __launch_bounds__(256) void k_dinv(const int* __restrict__ deg,
                                              float* __restrict__ dinv) {
    int v = blockIdx.x * 256 + threadIdx.x;
    if (v < N_NODES) dinv[v] = rsqrtf((float)deg[v] + 1.0f);
}

// ---- scan pass 1: per-block sums of deg ----
__global__ __launch_bounds__(256) void k_bsum(const int* __restrict__ deg,
                                              int* __restrict__ bsum) {
    __shared__ int sm[256];
    int i = blockIdx.x * 256 + threadIdx.x;
    sm[threadIdx.x] = (i < N_NODES) ? deg[i] : 0;
    __syncthreads();
    for (int s = 128; s > 0; s >>= 1) {
        if (threadIdx.x < s) sm[threadIdx.x] += sm[threadIdx.x + s];
        __syncthreads();
    }
    if (threadIdx.x == 0) bsum[blockIdx.x] = sm[0];
}

// ---- scan pass 2: exclusive scan of block sums (single block, 512 thr) ----
__global__ __launch_bounds__(512) void k_scanb(int* __restrict__ bsum) {
    __shared__ int sm[512];
    int t = threadIdx.x;
    sm[t] = (t < NBLK) ? bsum[t] : 0;
    __syncthreads();
    for (int off = 1; off < 512; off <<= 1) {
        int v = (t >= off) ? sm[t - off] : 0;
        __syncthreads();
        sm[t] += v;
        __syncthreads();
    }
    if (t < NBLK) bsum[t] = (t > 0) ? sm[t - 1] : 0;
}

// ---- scan pass 3: per-block exclusive scan + block offset -> start[] ----
__global__ __launch_bounds__(256) void k_scanf(const int* __restrict__ deg,
                                               const int* __restrict__ boff,
                                               int* __restrict__ start) {
    __shared__ int sm[256];
    int i = blockIdx.x * 256 + threadIdx.x;
    int v = (i < N_NODES) ? deg[i] : 0;
    sm[threadIdx.x] = v;
    __syncthreads();
    for (int off = 1; off < 256; off <<= 1) {
        int u = (threadIdx.x >= off) ? sm[threadIdx.x - off] : 0;
        __syncthreads();
        sm[threadIdx.x] += u;
        __syncthreads();
    }
    int excl = sm[threadIdx.x] - v + boff[blockIdx.x];
    if (i < N_NODES) start[i] = excl;
    if (i == N_NODES - 1) start[N_NODES] = excl + v;
}

// ---- bucket edges into CSR: csr[start[c]+pos] = src ----
__global__ __launch_bounds__(256) void k_bucket(const int* __restrict__ ei,
                                                const int* __restrict__ start,
                                                int* __restrict__ cnt,
                                                int* __restrict__ csr) {
    int e = blockIdx.x * 256 + threadIdx.x;
    if (e < N_EDGES) {
        int r = ei[e];
        int c = ei[N_EDGES + e];
        int p = atomicAdd(&cnt[c], 1);
        csr[start[c] + p] = r;
    }
}

// ---- layer1 GEMM: g[v,j] = dinv[v] * sum_k x[v,k]*W1[k,j]  (64x64) ----
__global__ __launch_bounds__(256) void k_gemm1(const float* __restrict__ x,
                                               const float* __restrict__ W,
                                               const float* __restrict__ dinv,
                                               float* __restrict__ g) {
    __shared__ float Ws[64 * 64];
    __shared__ float xs[4][64];
    int tid = threadIdx.x;
    for (int i = tid; i < 64 * 64; i += 256) Ws[i] = W[i];
    int v0 = blockIdx.x * 4;
    for (int i = tid; i < 4 * 64; i += 256) xs[i >> 6][i & 63] = x[v0 * 64 + i];
    __syncthreads();
    int r = tid >> 6, j = tid & 63;
    float acc = 0.f;
#pragma unroll
    for (int k = 0; k < 64; k++) acc += xs[r][k] * Ws[k * 64 + j];
    int v = v0 + r;
    g[v * 64 + j] = acc * dinv[v];
}

// ---- agg1: wave per node; gather in-neighbors, fused bias+ReLU -> h ----
__global__ __launch_bounds__(256) void k_agg1(const int* __restrict__ csr,
                                              const int* __restrict__ start,
                                              const float* __restrict__ g,
                                              const float* __restrict__ dinv,
                                              const float* __restrict__ b1,
                                              float* __restrict__ h) {
    int j = threadIdx.x & 63;
    int v = blockIdx.x * 4 + (threadIdx.x >> 6);
    int s = start[v], e2 = start[v + 1];
    float acc = g[v * 64 + j];           // self-loop message
    for (int base = s; base < e2; base += 64) {
        int cnt = min(64, e2 - base);
        int rl = (j < cnt) ? csr[base + j] : 0;   // coalesced prefetch
#pragma unroll 4
        for (int i = 0; i < cnt; i++) {
            int r = __shfl(rl, i, 64);
            acc += g[r * 64 + j];        // independent loads -> ILP
        }
    }
    float hv = dinv[v] * acc + b1[j];
    h[v * 64 + j] = hv > 0.f ? hv : 0.f;
}

// ---- layer2 GEMM: g2[v,j] = dinv[v] * sum_k h[v,k]*W2[k,j]  (64x40) ----
__global__ __launch_bounds__(256) void k_gemm2(const float* __restrict__ h,
                                               const float* __restrict__ W,
                                               const float* __restrict__ dinv,
                                               float* __restrict__ g2) {
    __shared__ float Ws[64 * 40];
    __shared__ float hs[4][64];
    int tid = threadIdx.x;
    for (int i = tid; i < 64 * 40; i += 256) Ws[i] = W[i];
    int v0 = blockIdx.x * 4;
    for (int i = tid; i < 4 * 64; i += 256) hs[i >> 6][i & 63] = h[v0 * 64 + i];
    __syncthreads();
    int r = tid >> 6, j = tid & 63;
    if (j < 40) {
        float acc = 0.f;
#pragma unroll
        for (int k = 0; k < 64; k++) acc += hs[r][k] * Ws[k * 40 + j];
        int v = v0 + r;
        g2[v * 40 + j] = acc * dinv[v];
    }
}

// ---- agg2: wave per node; gather + fused bias + log_softmax -> out ----
__global__ __launch_bounds__(256) void k_agg2(const int* __restrict__ csr,
                                              const int* __restrict__ start,
                                              const float* __restrict__ g2,
                                              const float* __restrict__ dinv,
                                              const float* __restrict__ b2v,
                                              float* __restrict__ out) {
    int j = threadIdx.x & 63;
    int v = blockIdx.x * 4 + (threadIdx.x >> 6);
    int s = start[v], e2 = start[v + 1];
    // lanes >= 40 read in-bounds garbage (g2 region is N*64 floats); unused.
    float acc = g2[v * 40 + ((j < 40) ? j : 0)];
    for (int base = s; base < e2; base += 64) {
        int cnt = min(64, e2 - base);
        int rl = (j < cnt) ? csr[base + j] : 0;
#pragma unroll 4
        for (int i = 0; i < cnt; i++) {
            int r = __shfl(rl, i, 64);
            acc += g2[r * 40 + ((j < 40) ? j : 0)];
        }
    }
    float logit = (j < D_OUT) ? dinv[v] * acc + b2v[j] : -INFINITY;
    float m = logit;
#pragma unroll
    for (int o = 32; o > 0; o >>= 1) m = fmaxf(m, __shfl_xor(m, o, 64));
    float ex = (j < D_OUT) ? expf(logit - m) : 0.f;
    float ssum = ex;
#pragma unroll
    for (int o = 32; o > 0; o >>= 1) ssum += __shfl_xor(ssum, o, 64);
    if (j < D_OUT) out[v * D_OUT + j] = logit - m - logf(ssum);
}

extern "C" void kernel_launch(void* const* d_in, const int* in_sizes, int n_in,
                              void* d_out, int out_size, void* d_ws, size_t ws_size,
                              hipStream_t stream) {
    const float* x  = (const float*)d_in[0];
    const int*   ei = (const int*)d_in[1];
    const float* W1 = (const float*)d_in[2];
    const float* b1 = (const float*)d_in[3];
    const float* W2 = (const float*)d_in[4];
    const float* b2 = (const float*)d_in[5];
    float* out = (float*)d_out;

    const int N = N_NODES;
    // Workspace ~59 MB (R2 proved >= 68 MB available).
    int*   deg   = (int*)d_ws;                  // N
    int*   cnt   = deg + N;                     // N   (adjacent -> one zero pass)
    int*   start = cnt + N;                     // N+1
    int*   bsum  = start + N + 1;               // 512
    int*   csr   = bsum + 512;                  // E
    float* dinv  = (float*)(csr + N_EDGES);     // N
    float* g     = dinv + N;                    // N*64 (g1, then g2 packed N*40)
    float* h     = g + (size_t)N * 64;          // N*64

    k_zero<<<(2 * N + 255) / 256, 256, 0, stream>>>(deg, 2 * N);
    k_deg<<<(N_EDGES + 255) / 256, 256, 0, stream>>>(ei + N_EDGES, deg);
    k_dinv<<<NBLK, 256, 0, stream>>>(deg, dinv);
    k_bsum<<<NBLK, 256, 0, stream>>>(deg, bsum);
    k_scanb<<<1, 512, 0, stream>>>(bsum);
    k_scanf<<<NBLK, 256, 0, stream>>>(deg, bsum, start);
    k_bucket<<<(N_EDGES + 255) / 256, 256, 0, stream>>>(ei, start, cnt, csr);
    k_gemm1<<<N / 4, 256, 0, stream>>>(x, W1, dinv, g);
    k_agg1<<<N / 4, 256, 0, stream>>>(csr, start, g, dinv, b1, h);
    k_gemm2<<<N / 4, 256, 0, stream>>>(h, W2, dinv, g);
    k_agg2<<<N / 4, 256, 0, stream>>>(csr, start, g, dinv, b2, out);
}

// Round 7
// 562.274 us; speedup vs baseline: 1.6001x; 1.0249x over previous
//
#include <hip/hip_runtime.h>
#include <hip/hip_bf16.h>
#include <math.h>

#define N_NODES 100000
#define N_EDGES 1600000
#define D_IN 64
#define D_HID 64
#define D_OUT 40
#define NBLK ((N_NODES + 255) / 256)   // 391 scan blocks

typedef __hip_bfloat16 bf16;

// ---- zero ints (no hipMemsetAsync) ----
__global__ __launch_bounds__(256) void k_zero(int* __restrict__ p, int n) {
    int i = blockIdx.x * 256 + threadIdx.x;
    if (i < n) p[i] = 0;
}

// ---- in-degree histogram over real edges ----
__global__ __launch_bounds__(256) void k_deg(const int* __restrict__ col,
                                             int* __restrict__ deg) {
    int e = blockIdx.x * 256 + threadIdx.x;
    if (e < N_EDGES) atomicAdd(&deg[col[e]], 1);
}

// ---- dinv = rsqrt(deg + 1)  (self-loop in the +1) ----
__global__ __launch_bounds__(256) void k_dinv(const int* __restrict__ deg,
                                              float* __restrict__ dinv) {
    int v = blockIdx.x * 256 + threadIdx.x;
    if (v < N_NODES) dinv[v] = rsqrtf((float)deg[v] + 1.0f);
}

// ---- scan pass 1: per-block sums of deg ----
__global__ __launch_bounds__(256) void k_bsum(const int* __restrict__ deg,
                                              int* __restrict__ bsum) {
    __shared__ int sm[256];
    int i = blockIdx.x * 256 + threadIdx.x;
    sm[threadIdx.x] = (i < N_NODES) ? deg[i] : 0;
    __syncthreads();
    for (int s = 128; s > 0; s >>= 1) {
        if (threadIdx.x < s) sm[threadIdx.x] += sm[threadIdx.x + s];
        __syncthreads();
    }
    if (threadIdx.x == 0) bsum[blockIdx.x] = sm[0];
}

// ---- scan pass 2: exclusive scan of block sums (single block) ----
__global__ __launch_bounds__(512) void k_scanb(int* __restrict__ bsum) {
    __shared__ int sm[512];
    int t = threadIdx.x;
    sm[t] = (t < NBLK) ? bsum[t] : 0;
    __syncthreads();
    for (int off = 1; off < 512; off <<= 1) {
        int v = (t >= off) ? sm[t - off] : 0;
        __syncthreads();
        sm[t] += v;
        __syncthreads();
    }
    if (t < NBLK) bsum[t] = (t > 0) ? sm[t - 1] : 0;
}

// ---- scan pass 3: per-block exclusive scan + block offset -> start[] ----
__global__ __launch_bounds__(256) void k_scanf(const int* __restrict__ deg,
                                               const int* __restrict__ boff,
                                               int* __restrict__ start) {
    __shared__ int sm[256];
    int i = blockIdx.x * 256 + threadIdx.x;
    int v = (i < N_NODES) ? deg[i] : 0;
    sm[threadIdx.x] = v;
    __syncthreads();
    for (int off = 1; off < 256; off <<= 1) {
        int u = (threadIdx.x >= off) ? sm[threadIdx.x - off] : 0;
        __syncthreads();
        sm[threadIdx.x] += u;
        __syncthreads();
    }
    int excl = sm[threadIdx.x] - v + boff[blockIdx.x];
    if (i < N_NODES) start[i] = excl;
    if (i == N_NODES - 1) start[N_NODES] = excl + v;
}

// ---- bucket edges into CSR: csr[start[c]+pos] = src ----
__global__ __launch_bounds__(256) void k_bucket(const int* __restrict__ ei,
                                                const int* __restrict__ start,
                                                int* __restrict__ cnt,
                                                int* __restrict__ csr) {
    int e = blockIdx.x * 256 + threadIdx.x;
    if (e < N_EDGES) {
        int r = ei[e];
        int c = ei[N_EDGES + e];
        int p = atomicAdd(&cnt[c], 1);
        csr[start[c] + p] = r;
    }
}

// ---- layer1 GEMM: gb[v,j] = bf16( dinv[v] * sum_k x[v,k]*W1[k,j] ) ----
__global__ __launch_bounds__(256) void k_gemm1(const float* __restrict__ x,
                                               const float* __restrict__ W,
                                               const float* __restrict__ dinv,
                                               bf16* __restrict__ gb) {
    __shared__ float Ws[64 * 64];
    __shared__ float xs[4][64];
    int tid = threadIdx.x;
    for (int i = tid; i < 64 * 64; i += 256) Ws[i] = W[i];
    int v0 = blockIdx.x * 4;
    for (int i = tid; i < 4 * 64; i += 256) xs[i >> 6][i & 63] = x[v0 * 64 + i];
    __syncthreads();
    int r = tid >> 6, j = tid & 63;
    float acc = 0.f;
#pragma unroll
    for (int k = 0; k < 64; k++) acc += xs[r][k] * Ws[k * 64 + j];
    int v = v0 + r;
    gb[v * 64 + j] = __float2bfloat16(acc * dinv[v]);
}

// ---- agg1: wave per node; bf16 gather, fp32 accumulate, bias+ReLU -> h ----
__global__ __launch_bounds__(256) void k_agg1(const int* __restrict__ csr,
                                              const int* __restrict__ start,
                                              const bf16* __restrict__ gb,
                                              const float* __restrict__ dinv,
                                              const float* __restrict__ b1,
                                              float* __restrict__ h) {
    int j = threadIdx.x & 63;
    int v = blockIdx.x * 4 + (threadIdx.x >> 6);
    int s = start[v], e2 = start[v + 1];
    float acc = __bfloat162float(gb[v * 64 + j]);   // self-loop message
    for (int base = s; base < e2; base += 64) {
        int cnt = min(64, e2 - base);
        int rl = (j < cnt) ? csr[base + j] : 0;     // coalesced prefetch
#pragma unroll 8
        for (int i = 0; i < cnt; i++) {
            int r = __shfl(rl, i, 64);
            acc += __bfloat162float(gb[r * 64 + j]);
        }
    }
    float hv = dinv[v] * acc + b1[j];
    h[v * 64 + j] = hv > 0.f ? hv : 0.f;
}

// ---- layer2 GEMM: g2b[v,j] = bf16( dinv[v] * sum_k h[v,k]*W2[k,j] ) ----
__global__ __launch_bounds__(256) void k_gemm2(const float* __restrict__ h,
                                               const float* __restrict__ W,
                                               const float* __restrict__ dinv,
                                               bf16* __restrict__ g2b) {
    __shared__ float Ws[64 * 40];
    __shared__ float hs[4][64];
    int tid = threadIdx.x;
    for (int i = tid; i < 64 * 40; i += 256) Ws[i] = W[i];
    int v0 = blockIdx.x * 4;
    for (int i = tid; i < 4 * 64; i += 256) hs[i >> 6][i & 63] = h[v0 * 64 + i];
    __syncthreads();
    int r = tid >> 6, j = tid & 63;
    if (j < 40) {
        float acc = 0.f;
#pragma unroll
        for (int k = 0; k < 64; k++) acc += hs[r][k] * Ws[k * 40 + j];
        int v = v0 + r;
        g2b[v * 40 + j] = __float2bfloat16(acc * dinv[v]);
    }
}

// ---- agg2: wave per node; bf16 gather + bias + log_softmax -> out ----
__global__ __launch_bounds__(256) void k_agg2(const int* __restrict__ csr,
                                              const int* __restrict__ start,
                                              const bf16* __restrict__ g2b,
                                              const float* __restrict__ dinv,
                                              const float* __restrict__ b2v,
                                              float* __restrict__ out) {
    int j = threadIdx.x & 63;
    int v = blockIdx.x * 4 + (threadIdx.x >> 6);
    int s = start[v], e2 = start[v + 1];
    int jc = (j < D_OUT) ? j : 0;   // lanes >= 40 read in-bounds, unused
    float acc = __bfloat162float(g2b[v * 40 + jc]);
    for (int base = s; base < e2; base += 64) {
        int cnt = min(64, e2 - base);
        int rl = (j < cnt) ? csr[base + j] : 0;
#pragma unroll 8
        for (int i = 0; i < cnt; i++) {
            int r = __shfl(rl, i, 64);
            acc += __bfloat162float(g2b[r * 40 + jc]);
        }
    }
    float logit = (j < D_OUT) ? dinv[v] * acc + b2v[j] : -INFINITY;
    float m = logit;
#pragma unroll
    for (int o = 32; o > 0; o >>= 1) m = fmaxf(m, __shfl_xor(m, o, 64));
    float ex = (j < D_OUT) ? expf(logit - m) : 0.f;
    float ssum = ex;
#pragma unroll
    for (int o = 32; o > 0; o >>= 1) ssum += __shfl_xor(ssum, o, 64);
    if (j < D_OUT) out[v * D_OUT + j] = logit - m - logf(ssum);
}

extern "C" void kernel_launch(void* const* d_in, const int* in_sizes, int n_in,
                              void* d_out, int out_size, void* d_ws, size_t ws_size,
                              hipStream_t stream) {
    const float* x  = (const float*)d_in[0];
    const int*   ei = (const int*)d_in[1];
    const float* W1 = (const float*)d_in[2];
    const float* b1 = (const float*)d_in[3];
    const float* W2 = (const float*)d_in[4];
    const float* b2 = (const float*)d_in[5];
    float* out = (float*)d_out;

    const int N = N_NODES;
    // Workspace ~47 MB.
    int*   deg   = (int*)d_ws;                  // N
    int*   cnt   = deg + N;                     // N (adjacent -> one zero pass)
    int*   start = cnt + N;                     // N+1
    int*   bsum  = start + N + 1;               // 512
    int*   csr   = bsum + 512;                  // E
    float* dinv  = (float*)(csr + N_EDGES);     // N
    bf16*  gb    = (bf16*)(dinv + N);           // N*64 bf16 (g1; reused as g2 N*40)
    float* h     = (float*)(gb + (size_t)N * 64); // N*64 fp32

    k_zero<<<(2 * N + 255) / 256, 256, 0, stream>>>(deg, 2 * N);
    k_deg<<<(N_EDGES + 255) / 256, 256, 0, stream>>>(ei + N_EDGES, deg);
    k_dinv<<<NBLK, 256, 0, stream>>>(deg, dinv);
    k_bsum<<<NBLK, 256, 0, stream>>>(deg, bsum);
    k_scanb<<<1, 512, 0, stream>>>(bsum);
    k_scanf<<<NBLK, 256, 0, stream>>>(deg, bsum, start);
    k_bucket<<<(N_EDGES + 255) / 256, 256, 0, stream>>>(ei, start, cnt, csr);
    k_gemm1<<<N / 4, 256, 0, stream>>>(x, W1, dinv, gb);
    k_agg1<<<N / 4, 256, 0, stream>>>(csr, start, gb, dinv, b1, h);
    k_gemm2<<<N / 4, 256, 0, stream>>>(h, W2, dinv, gb);
    k_agg2<<<N / 4, 256, 0, stream>>>(csr, start, gb, dinv, b2, out);
}